// Round 17
// baseline (108.316 us; speedup 1.0000x reference)
//
#include <hip/hip_runtime.h>
#include <hip/hip_bf16.h>

// DiffRenderer v16: PERSISTENT software-pipelined blocks.
// Ledger: nt stores +14us; staged reads +1.3us; everything else null/neg.
// Residual model: per-generation serialized read+softmax phase (~15us with
// no store traffic) + write phase at ~fill rate. v16: grid=768=3 blocks/CU
// exactly resident, each block does 3 chunks; next chunk's global_load_lds
// (into buffer A) issues right after softmax consumes A, hiding the read
// under the current chunk's 28-row store loop. h-loop LDS ops touch only
// buffer B (probs ROW_U=72 + f32 stage overlay) -> no conflict with A DMA.
// Boundary s_waitcnt vmcnt(0) guarantees A landed before next softmax.
#define ROWS 384
#define COLS 768
#define NCH  69
#define CH   28
#define CW   14
#define KP   96             // font K padded to 3 k-steps of 32 (zeros past 68)
#define IMG_W 10752
#define ROW_U 72            // prob-row stride in ushorts (144B; k69..71 = 0)
#define CHUNK_B (64 * NCH * 4)   // 17664 B logits chunk per wave
#define PROB_B  (64 * ROW_U * 2) // 9216 B prob region per wave
#define NCHUNKS (ROWS * COLS / 128)  // 2304 (128 cells per chunk)
#define BLOCKS_P 768
#define CPB 3                // chunks per block

typedef __attribute__((ext_vector_type(8))) short bfrag;   // 8 bf16 (4 VGPR)
typedef __attribute__((ext_vector_type(4))) float f32x4;   // C/D frag / stores

__device__ __forceinline__ unsigned bf16bits(float x) {
    unsigned b = __float_as_uint(x);
    b += 0x7FFFu + ((b >> 16) & 1u);   // RTNE
    return b >> 16;
}

__device__ __forceinline__ void gload_lds16(const void* g, void* l) {
    __builtin_amdgcn_global_load_lds(
        (const __attribute__((address_space(1))) void*)g,
        (__attribute__((address_space(3))) void*)l, 16, 0, 0);
}

// ---- kernel 1: font (69,28,14) f32 -> Fh[28][16][96] bf16 (zero-padded) ----
__global__ __launch_bounds__(256)
void font_prep(const float* __restrict__ font, unsigned short* __restrict__ Fh) {
    int idx = blockIdx.x * 256 + threadIdx.x;        // 43008
    if (idx >= CH * 16 * KP) return;
    int k  = idx % KP;
    int hw = idx / KP;
    int w  = hw % 16, h = hw / 16;
    float v = (w < CW && k < NCH) ? font[k * (CH * CW) + h * CW + w] : 0.f;
    Fh[idx] = (unsigned short)bf16bits(v);
}

// ---- kernel 2: persistent pipelined softmax+MFMA+nt-store ----
__global__ __launch_bounds__(128)
void diffrender_v16(const float* __restrict__ logits,       // (294912,69) f32
                    const unsigned short* __restrict__ Fh,  // (28,16,96) bf16
                    float* __restrict__ out)                // (10752,10752) f32
{
    __shared__ __align__(16) unsigned char bufA[2][CHUNK_B]; // 35.3 KB staging
    __shared__ __align__(16) unsigned char bufB[2][PROB_B];  // 18.4 KB probs/stage

    const int tid  = threadIdx.x;
    const int lane = tid & 63;
    const int wv   = tid >> 6;
    unsigned char* A = bufA[wv];
    unsigned char* B = bufB[wv];

    const int w15   = lane & 15;
    const int g     = lane >> 4;
    const int kgrp  = g * 8;
    const int crow4 = g * 4;
    const unsigned short* fb = Fh + (size_t)w15 * KP + kgrp;

    int cid = blockIdx.x;                    // chunk c*768 + bid, c=0

    // prologue: stage chunk 0 into A
    {
        const char* gb = (const char*)logits + (size_t)(cid * 128 + wv * 64) * (NCH * 4);
#pragma unroll
        for (int i = 0; i < 18; ++i) {
            const int off = (i < 17) ? i * 1024 : (CHUNK_B - 1024);
            gload_lds16(gb + off + lane * 16, (void*)(A + off));
        }
    }

#pragma unroll 1
    for (int c = 0; c < CPB; ++c) {
        asm volatile("s_waitcnt vmcnt(0)" ::: "memory");   // A landed (+ store drain)

        const int r  = cid / 6;
        const int cb = (cid % 6) * 128;

        // ---- softmax from own row of A ----
        const float* myrow = (const float*)(A + (size_t)lane * (NCH * 4));
        float e[NCH];
        float m = -INFINITY;
#pragma unroll
        for (int n = 0; n < NCH; ++n) { e[n] = myrow[n]; m = fmaxf(m, e[n]); }
        float s = 0.f;
#pragma unroll
        for (int n = 0; n < NCH; ++n) { e[n] = __expf(e[n] - m); s += e[n]; }
        const float inv = 1.f / s;

        // A fully consumed (e[] data-dependency drained lgkm); prefetch next
        if (c + 1 < CPB) {
            asm volatile("s_waitcnt lgkmcnt(0)" ::: "memory");
            const char* gb = (const char*)logits
                           + (size_t)((cid + BLOCKS_P) * 128 + wv * 64) * (NCH * 4);
#pragma unroll
            for (int i = 0; i < 18; ++i) {
                const int off = (i < 17) ? i * 1024 : (CHUNK_B - 1024);
                gload_lds16(gb + off + lane * 16, (void*)(A + off));
            }
        }

        // ---- pack probs bf16 -> B (rows of ROW_U=72 ushorts) ----
        unsigned* prow = (unsigned*)(B + (size_t)lane * (ROW_U * 2));
#pragma unroll
        for (int i = 0; i < 34; ++i)
            prow[i] = bf16bits(e[2 * i] * inv) | (bf16bits(e[2 * i + 1] * inv) << 16);
        prow[34] = bf16bits(e[68] * inv);          // k68 | 0
        prow[35] = 0;                              // k70,71 = 0

        // ---- A-frags from B (4 M-tiles x 3 k-steps, shared-ks2 trick) ----
        const unsigned short* pa = (const unsigned short*)B;
        bfrag a[4][3];
#pragma unroll
        for (int mt = 0; mt < 4; ++mt) {
            const size_t base = (size_t)(mt * 16 + w15) * ROW_U;
            a[mt][0] = *(const bfrag*)&pa[base + kgrp];
            a[mt][1] = *(const bfrag*)&pa[base + 32 + kgrp];
            a[mt][2] = *(const bfrag*)&pa[base + 64];  // k64..71; font k>=69 = 0
        }

        // B dead after frag reads -> reuse as f32 stage (2 rows x 896 = 7168B)
        float* stage = (float*)B;

        // ---- h loop: 2 image rows/iter, double-buffered font ----
        bfrag bcur[2][3], bnxt[2][3];
#pragma unroll
        for (int hh = 0; hh < 2; ++hh)
#pragma unroll
            for (int ks = 0; ks < 3; ++ks)
                bcur[hh][ks] = *(const bfrag*)(fb + (size_t)(hh * 16) * KP + ks * 32);

#pragma unroll 1
        for (int h2 = 0; h2 < CH / 2; ++h2) {
            const int h = 2 * h2;
            if (h2 + 1 < CH / 2) {
                const unsigned short* fn = fb + (size_t)((h + 2) * 16) * KP;
#pragma unroll
                for (int hh = 0; hh < 2; ++hh)
#pragma unroll
                    for (int ks = 0; ks < 3; ++ks)
                        bnxt[hh][ks] = *(const bfrag*)(fn + (size_t)(hh * 16) * KP + ks * 32);
            }

            f32x4 acc[2][4];
#pragma unroll
            for (int hh = 0; hh < 2; ++hh)
#pragma unroll
                for (int mt = 0; mt < 4; ++mt)
                    acc[hh][mt] = f32x4{0, 0, 0, 0};
#pragma unroll
            for (int hh = 0; hh < 2; ++hh)
#pragma unroll
                for (int mt = 0; mt < 4; ++mt)
#pragma unroll
                    for (int ks = 0; ks < 3; ++ks)
                        acc[hh][mt] = __builtin_amdgcn_mfma_f32_16x16x32_bf16(
                            a[mt][ks], bcur[hh][ks], acc[hh][mt], 0, 0, 0);

            if (w15 < CW) {
#pragma unroll
                for (int hh = 0; hh < 2; ++hh)
#pragma unroll
                    for (int mt = 0; mt < 4; ++mt)
#pragma unroll
                        for (int j = 0; j < 4; ++j)
                            stage[hh * 896 + (mt * 16 + crow4 + j) * CW + w15] = acc[hh][mt][j];
            }

#pragma unroll
            for (int hh = 0; hh < 2; ++hh) {
                f32x4* o4 = (f32x4*)(out + (size_t)(r * CH + h + hh) * IMG_W
                                         + (size_t)(cb + wv * 64) * CW);
                const f32x4* s4 = (const f32x4*)(stage + hh * 896);
#pragma unroll
                for (int i = 0; i < 4; ++i) {
                    const int idx = i * 64 + lane;
                    if (idx < 224) __builtin_nontemporal_store(s4[idx], &o4[idx]);
                }
            }

#pragma unroll
            for (int hh = 0; hh < 2; ++hh)
#pragma unroll
                for (int ks = 0; ks < 3; ++ks)
                    bcur[hh][ks] = bnxt[hh][ks];
        }

        cid += BLOCKS_P;
    }
}

extern "C" void kernel_launch(void* const* d_in, const int* in_sizes, int n_in,
                              void* d_out, int out_size, void* d_ws, size_t ws_size,
                              hipStream_t stream) {
    const float* logits = (const float*)d_in[0];   // (294912,69) f32
    const float* font   = (const float*)d_in[1];   // (69,28,14)  f32
    float* out          = (float*)d_out;           // (10752,10752) f32
    unsigned short* Fh  = (unsigned short*)d_ws;   // (28,16,96) bf16 = 86KB

    font_prep<<<(CH * 16 * KP + 255) / 256, 256, 0, stream>>>(font, Fh);

    diffrender_v16<<<BLOCKS_P, 128, 0, stream>>>(logits, Fh, out);
}